// Round 1
// 863.423 us; speedup vs baseline: 1.0865x; 1.0865x over previous
//
#include <hip/hip_runtime.h>
#include <stdint.h>

// Problem constants
#define NN 50000
#define NE 800000
#define NR 12
#define NRX 13                // 12 relations + root slot
#define NH 128
#define NF 1582
#define NSEG (NN * NR)        // 600000 (seg = d*12 + r)
#define MT 3125               // NN/16 row tiles (exact)
#define MT2 1563              // ceil(MT/2) for 32-row xw waves
#define SCAN_NB ((NSEG + 255) / 256)   // 2344
#define KSENC 50              // ceil(1582/32)
#define CTXW (NRX * 8)        // 104 col-tiles in stacked [128 x 13*128] weight

typedef __attribute__((ext_vector_type(8))) short short8;   // 8 x bf16
typedef __attribute__((ext_vector_type(4))) float floatx4;  // MFMA acc

__device__ __forceinline__ float bf2f(unsigned int u16) {
    union { unsigned int i; float f; } w; w.i = u16 << 16; return w.f;
}
__device__ __forceinline__ unsigned short f2bf(float f) {
    union { float f; unsigned int i; } w; w.f = f;
    unsigned int i = w.i;
    return (unsigned short)((i + 0x7FFFu + ((i >> 16) & 1u)) >> 16);  // RNE
}
__device__ __forceinline__ float leaky_f(float v) { return v > 0.f ? v : 0.01f * v; }
__device__ __forceinline__ float fast_rcp(float x) {
    float r; asm("v_rcp_f32 %0, %1" : "=v"(r) : "v"(x)); return r;
}

// ================= weight swizzles into MFMA B-fragment order =================
// layout: dst[((ct*KS+ks)*64+lane)*8 + j] = B[k][col], k=ks*32+(lane>>4)*8+j,
// col=ct*16+(lane&15). Zero outside valid k.
__global__ __launch_bounds__(256) void swz_k(
    const float* __restrict__ src1, int K1,
    const float* __restrict__ src2, int Ktot, int N, int KS,
    unsigned short* __restrict__ dst)
{
    const int idx = blockIdx.x * 256 + threadIdx.x;
    const int total = (N >> 4) * KS * 512;
    if (idx >= total) return;
    const int j = idx & 7;
    const int lane = (idx >> 3) & 63;
    const int cks = idx >> 9;
    const int ks = cks % KS;
    const int ct = cks / KS;
    const int k = ks * 32 + (lane >> 4) * 8 + j;
    const int col = ct * 16 + (lane & 15);
    float v = 0.f;
    if (k < Ktot) v = (k < K1) ? src1[(size_t)k * N + col] : src2[(size_t)(k - K1) * N + col];
    dst[idx] = f2bf(v);
}

// Per-relation weights stacked along COLUMNS: B[k][r*128+c] = rgW[r][k][c], r=12 -> root.
// Fragment layout matches xw_k's load: dst[((ctg*4+ks)*64+lane)*8+j], ctg = r*8+ct8.
__global__ __launch_bounds__(256) void swzxw_k(
    const float* __restrict__ rgW, const float* __restrict__ root,
    unsigned short* __restrict__ dst)
{
    const int idx = blockIdx.x * 256 + threadIdx.x;
    const int total = CTXW * 4 * 512;   // 212992
    if (idx >= total) return;
    const int j = idx & 7;
    const int lane = (idx >> 3) & 63;
    const int cks = idx >> 9;
    const int ks = cks & 3;
    const int ctg = cks >> 2;           // 0..103
    const int r = ctg >> 3;             // 0..12
    const int ct8 = ctg & 7;
    const int k = ks * 32 + (lane >> 4) * 8 + j;
    const int c = ct8 * 16 + (lane & 15);
    const float v = (r < NR) ? rgW[((size_t)r * NH + k) * NH + c]
                             : root[(size_t)k * NH + c];
    dst[idx] = f2bf(v);
}

// Encoder block-diagonal B [1582(pad 1600) x 128]:
// cols 0..31: Wdes rows 46..814 | 32..63: Wtw rows 814..1582
// cols 64..95: Wnum rows 12..46 | 96..127: Wcat rows 0..12
__global__ __launch_bounds__(256) void swzenc_k(
    const float* __restrict__ Wdes, const float* __restrict__ Wtw,
    const float* __restrict__ Wnum, const float* __restrict__ Wcat,
    unsigned short* __restrict__ dst)
{
    const int idx = blockIdx.x * 256 + threadIdx.x;
    const int total = 8 * KSENC * 512;
    if (idx >= total) return;
    const int j = idx & 7;
    const int lane = (idx >> 3) & 63;
    const int cks = idx >> 9;
    const int ks = cks % KSENC;
    const int ct = cks / KSENC;
    const int k = ks * 32 + (lane >> 4) * 8 + j;
    const int col = ct * 16 + (lane & 15);
    float v = 0.f;
    if (col < 32) {
        if (k >= 46 && k < 814)   v = Wdes[(size_t)(k - 46) * 32 + col];
    } else if (col < 64) {
        if (k >= 814 && k < 1582) v = Wtw[(size_t)(k - 814) * 32 + (col - 32)];
    } else if (col < 96) {
        if (k >= 12 && k < 46)    v = Wnum[(size_t)(k - 12) * 32 + (col - 64)];
    } else {
        if (k < 12)               v = Wcat[(size_t)k * 32 + (col - 96)];
    }
    dst[idx] = f2bf(v);
}

__global__ __launch_bounds__(128) void packbias_k(
    const float* __restrict__ bdes, const float* __restrict__ btw,
    const float* __restrict__ bnum, const float* __restrict__ bcat,
    float* __restrict__ be)
{
    const int c = threadIdx.x;
    float v;
    if (c < 32) v = bdes[c];
    else if (c < 64) v = btw[c - 32];
    else if (c < 96) v = bnum[c - 64];
    else v = bcat[c - 96];
    be[c] = v;
}

// ================= CSR build =================
__global__ __launch_bounds__(256) void hist_k(const int* __restrict__ dst,
                                              const int* __restrict__ et,
                                              int* __restrict__ deg)
{
    const int e = blockIdx.x * 256 + threadIdx.x;
    if (e >= NE) return;
    atomicAdd(&deg[dst[e] * NR + et[e]], 1);
}

__global__ __launch_bounds__(256) void scanA_k(const int* __restrict__ deg,
                                               int* __restrict__ offs,
                                               int* __restrict__ part)
{
    __shared__ int lds[256];
    const int i = blockIdx.x * 256 + threadIdx.x;
    const int v = (i < NSEG) ? deg[i] : 0;
    lds[threadIdx.x] = v; __syncthreads();
#pragma unroll
    for (int d = 1; d < 256; d <<= 1) {
        const int t = (threadIdx.x >= d) ? lds[threadIdx.x - d] : 0;
        __syncthreads();
        lds[threadIdx.x] += t;
        __syncthreads();
    }
    if (i < NSEG) offs[i] = lds[threadIdx.x] - v;
    if (threadIdx.x == 255) part[blockIdx.x] = lds[255];
}

__global__ __launch_bounds__(256) void scanB_k(int* __restrict__ part, int nb)
{
    __shared__ int lds[256];
    __shared__ int carry;
    if (threadIdx.x == 0) carry = 0;
    __syncthreads();
    for (int base = 0; base < nb; base += 256) {
        const int i = base + threadIdx.x;
        const int v = (i < nb) ? part[i] : 0;
        lds[threadIdx.x] = v; __syncthreads();
#pragma unroll
        for (int d = 1; d < 256; d <<= 1) {
            const int t = (threadIdx.x >= d) ? lds[threadIdx.x - d] : 0;
            __syncthreads();
            lds[threadIdx.x] += t;
            __syncthreads();
        }
        if (i < nb) part[i] = lds[threadIdx.x] - v + carry;
        __syncthreads();
        if (threadIdx.x == 255) carry += lds[255];
        __syncthreads();
    }
}

__global__ __launch_bounds__(256) void scanC_k(int* __restrict__ offs,
                                               const int* __restrict__ part)
{
    const int i = blockIdx.x * 256 + threadIdx.x;
    if (i < NSEG) offs[i] += part[blockIdx.x];
}

// pack (xw row index = src*13 + r) | deg<<20 so the gather loop is uniform over r
__global__ __launch_bounds__(256) void fill_k(const int* __restrict__ src,
                                              const int* __restrict__ dst,
                                              const int* __restrict__ et,
                                              const int* __restrict__ offs,
                                              const int* __restrict__ deg,
                                              int* __restrict__ cur,
                                              unsigned int* __restrict__ eidx)
{
    const int e = blockIdx.x * 256 + threadIdx.x;
    if (e >= NE) return;
    const int r = et[e];
    const int s = dst[e] * NR + r;
    const int pos = offs[s] + atomicAdd(&cur[s], 1);
    int n = deg[s]; if (n > 4095) n = 4095;
    eidx[pos] = (unsigned int)(src[e] * NRX + r) | ((unsigned int)n << 20);
}

// ================= fused encoder: feat -> blockdiag GEMM -> leaky -> W_in -> xa ===========
__global__ __launch_bounds__(256) void enc_k(
    const float* __restrict__ feat,
    const unsigned short* __restrict__ Benc, const float* __restrict__ be,
    const unsigned short* __restrict__ Bwin, const float* __restrict__ bin,
    unsigned short* __restrict__ xa)
{
    const int wave = threadIdx.x >> 6, lane = threadIdx.x & 63;
    const int q = lane >> 4, cl = lane & 15;
    int tile = blockIdx.x * 4 + wave;
    if (tile >= MT) tile = MT - 1;          // duplicate work; identical stores (benign)
    const int row = tile * 16 + cl;

    // active ks ranges per col-tile: des[46,814) tw[814,1582) num[12,46) cat[0,12)
    const int lo[8] = {1, 1, 25, 25, 0, 0, 0, 0};
    const int hi[8] = {26, 26, 50, 50, 2, 2, 1, 1};

    floatx4 acc[8];
#pragma unroll
    for (int ct = 0; ct < 8; ct++) { floatx4 z = {0.f,0.f,0.f,0.f}; acc[ct] = z; }

    for (int ks = 0; ks < KSENC; ks++) {
        const int kb = ks * 32 + q * 8;
        union { short8 v; unsigned short u[8]; } a;
        const float* ap = feat + (size_t)row * NF + kb;
        if (kb + 7 < NF) {
#pragma unroll
            for (int j = 0; j < 4; j++) {
                const float2 t = *(const float2*)__builtin_assume_aligned(ap + 2 * j, 8);
                a.u[2 * j]     = f2bf(t.x);
                a.u[2 * j + 1] = f2bf(t.y);
            }
        } else {
#pragma unroll
            for (int j = 0; j < 8; j++)
                a.u[j] = ((kb + j) < NF) ? f2bf(ap[j]) : 0;
        }
#pragma unroll
        for (int ct = 0; ct < 8; ct++) {
            if (ks >= lo[ct] && ks < hi[ct]) {
                const short8 b = *(const short8*)(Benc + ((size_t)(ct * KSENC + ks) * 64 + lane) * 8);
                acc[ct] = __builtin_amdgcn_mfma_f32_16x16x32_bf16(a.v, b, acc[ct], 0, 0, 0);
            }
        }
    }

    // leaky(acc + bias) -> LDS tile (C-layout -> A-layout transpose)
    __shared__ unsigned short lds[4][16][136];   // +8 pad: 2-way banks only
#pragma unroll
    for (int ct = 0; ct < 8; ct++) {
        const int col = ct * 16 + cl;
        const float bv = be[col];
#pragma unroll
        for (int r = 0; r < 4; r++)
            lds[wave][q * 4 + r][col] = f2bf(leaky_f(acc[ct][r] + bv));
    }
    __syncthreads();   // all 256 threads active (tile clamped)

    // W_in stage: A from LDS
    floatx4 acc2[8];
#pragma unroll
    for (int ct = 0; ct < 8; ct++) { floatx4 z = {0.f,0.f,0.f,0.f}; acc2[ct] = z; }
#pragma unroll
    for (int ks2 = 0; ks2 < 4; ks2++) {
        const short8 a2 = *(const short8*)&lds[wave][cl][ks2 * 32 + q * 8];
#pragma unroll
        for (int ct = 0; ct < 8; ct++) {
            const short8 b = *(const short8*)(Bwin + ((size_t)(ct * 4 + ks2) * 64 + lane) * 8);
            acc2[ct] = __builtin_amdgcn_mfma_f32_16x16x32_bf16(a2, b, acc2[ct], 0, 0, 0);
        }
    }
#pragma unroll
    for (int ct = 0; ct < 8; ct++) {
        const int col = ct * 16 + cl;
        const float bv = bin[col];
#pragma unroll
        for (int r = 0; r < 4; r++)
            xa[(size_t)(tile * 16 + q * 4 + r) * NH + col] = f2bf(leaky_f(acc2[ct][r] + bv));
    }
}

// ============ RGCN layer, stage 1: xw[n, r, :] = x[n] @ W_r  (r=12 -> root) ============
// 32 rows per wave (two 16-row subtiles share B fragments -> halves L2 B traffic)
__global__ __launch_bounds__(256) void xw_k(
    const unsigned short* __restrict__ xin,
    const unsigned short* __restrict__ Bxw,
    unsigned short* __restrict__ xw)
{
    const int wave = threadIdx.x >> 6, lane = threadIdx.x & 63;
    const int q = lane >> 4, cl = lane & 15;
    const int wid = blockIdx.x * 4 + wave;
    if (wid >= MT2 * NRX) return;
    const int t2 = wid / NRX;
    const int r = wid - t2 * NRX;
    const int ta = t2 * 2;
    const int tb = (ta + 1 < MT) ? ta + 1 : MT - 1;   // clamp: duplicate identical stores

    floatx4 accA[8], accB[8];
#pragma unroll
    for (int ct = 0; ct < 8; ct++) {
        floatx4 z = {0.f,0.f,0.f,0.f}; accA[ct] = z; accB[ct] = z;
    }
#pragma unroll
    for (int ks = 0; ks < 4; ks++) {
        const short8 aA = *(const short8*)__builtin_assume_aligned(
            xin + (size_t)(ta * 16 + cl) * NH + ks * 32 + q * 8, 16);
        const short8 aB = *(const short8*)__builtin_assume_aligned(
            xin + (size_t)(tb * 16 + cl) * NH + ks * 32 + q * 8, 16);
#pragma unroll
        for (int ct = 0; ct < 8; ct++) {
            const short8 b = *(const short8*)(Bxw + ((size_t)((r * 8 + ct) * 4 + ks) * 64 + lane) * 8);
            accA[ct] = __builtin_amdgcn_mfma_f32_16x16x32_bf16(aA, b, accA[ct], 0, 0, 0);
            accB[ct] = __builtin_amdgcn_mfma_f32_16x16x32_bf16(aB, b, accB[ct], 0, 0, 0);
        }
    }
#pragma unroll
    for (int ct = 0; ct < 8; ct++) {
        const int col = ct * 16 + cl;
#pragma unroll
        for (int rr = 0; rr < 4; rr++) {
            xw[((size_t)(ta * 16 + q * 4 + rr) * NRX + r) * NH + col] = f2bf(accA[ct][rr]);
            xw[((size_t)(tb * 16 + q * 4 + rr) * NRX + r) * NH + col] = f2bf(accB[ct][rr]);
        }
    }
}

// ============ RGCN layer, stage 2: uniform per-node gather-sum of transformed rows ======
// out[d] = sum_{e in edges(d)} (1/n_e) * xw[src_e, r_e]  +  xw[d, 12]  + bias
#define ACC8(fk, t, w) \
    fk[0] += (w) * bf2f(t.x & 0xFFFFu); fk[1] += (w) * bf2f(t.x >> 16); \
    fk[2] += (w) * bf2f(t.y & 0xFFFFu); fk[3] += (w) * bf2f(t.y >> 16); \
    fk[4] += (w) * bf2f(t.z & 0xFFFFu); fk[5] += (w) * bf2f(t.z >> 16); \
    fk[6] += (w) * bf2f(t.w & 0xFFFFu); fk[7] += (w) * bf2f(t.w >> 16);

__global__ __launch_bounds__(256) void gather_k(
    const unsigned short* __restrict__ xw,
    const unsigned int* __restrict__ eidx,
    const int* __restrict__ offs,
    const float* __restrict__ rbias,
    unsigned short* __restrict__ xout)
{
    const int wave = threadIdx.x >> 6, lane = threadIdx.x & 63;
    const int q = lane >> 4, cl = lane & 15;
    const int tile = blockIdx.x * 4 + wave;
    if (tile >= MT) return;                  // no LDS/barrier in this kernel
    const int d = tile * 16 + cl;
    const int beg = offs[d * NR];
    const int end = (d < NN - 1) ? offs[(d + 1) * NR] : NE;

    float f[4][8];
    {   // root contribution, weight 1
        const unsigned short* xr = xw + ((size_t)d * NRX + NR) * NH + q * 8;
#pragma unroll
        for (int ki = 0; ki < 4; ki++) {
            const uint4 t = *(const uint4*)(xr + ki * 32);
            f[ki][0] = bf2f(t.x & 0xFFFFu); f[ki][1] = bf2f(t.x >> 16);
            f[ki][2] = bf2f(t.y & 0xFFFFu); f[ki][3] = bf2f(t.y >> 16);
            f[ki][4] = bf2f(t.z & 0xFFFFu); f[ki][5] = bf2f(t.z >> 16);
            f[ki][6] = bf2f(t.w & 0xFFFFu); f[ki][7] = bf2f(t.w >> 16);
        }
    }

    unsigned int vnext = (beg < end) ? eidx[beg] : 0u;
    for (int e = beg; e < end; ++e) {
        const unsigned int val = vnext;
        if (e + 1 < end) vnext = eidx[e + 1];           // 2-deep index pipeline
        const float w = fast_rcp((float)(val >> 20));    // 1/deg (deg >= 1)
        const unsigned short* xr = xw + (size_t)(val & 0xFFFFFu) * NH + q * 8;
        const uint4 t0 = *(const uint4*)(xr);
        const uint4 t1 = *(const uint4*)(xr + 32);
        const uint4 t2 = *(const uint4*)(xr + 64);
        const uint4 t3 = *(const uint4*)(xr + 96);
        ACC8(f[0], t0, w); ACC8(f[1], t1, w); ACC8(f[2], t2, w); ACC8(f[3], t3, w);
    }

#pragma unroll
    for (int ki = 0; ki < 4; ki++) {
        union { short8 v; unsigned short u[8]; } o;
#pragma unroll
        for (int m = 0; m < 8; m++)
            o.u[m] = f2bf(f[ki][m] + rbias[ki * 32 + q * 8 + m]);
        *(short8*)(xout + (size_t)d * NH + ki * 32 + q * 8) = o.v;
    }
}

// ============ fused head: leaky(xa@Wo1+b) then @Wo2+b2 -> out ============
__global__ __launch_bounds__(256) void head_k(
    const unsigned short* __restrict__ xa,
    const unsigned short* __restrict__ Bo1, const float* __restrict__ bo1,
    const float* __restrict__ Wo2, const float* __restrict__ bo2,
    float* __restrict__ out)
{
    const int wave = threadIdx.x >> 6, lane = threadIdx.x & 63;
    const int q = lane >> 4, cl = lane & 15;
    int tile = blockIdx.x * 4 + wave;
    if (tile >= MT) tile = MT - 1;           // clamp; duplicate identical stores

    floatx4 acc[8];
#pragma unroll
    for (int ct = 0; ct < 8; ct++) { floatx4 z = {0.f,0.f,0.f,0.f}; acc[ct] = z; }
#pragma unroll
    for (int ks = 0; ks < 4; ks++) {
        const short8 a = *(const short8*)__builtin_assume_aligned(
            xa + (size_t)(tile * 16 + cl) * NH + ks * 32 + q * 8, 16);
#pragma unroll
        for (int ct = 0; ct < 8; ct++) {
            const short8 b = *(const short8*)(Bo1 + ((size_t)(ct * 4 + ks) * 64 + lane) * 8);
            acc[ct] = __builtin_amdgcn_mfma_f32_16x16x32_bf16(a, b, acc[ct], 0, 0, 0);
        }
    }
    __shared__ unsigned short lds[4][16][136];
#pragma unroll
    for (int ct = 0; ct < 8; ct++) {
        const int col = ct * 16 + cl;
        const float bv = bo1[col];
#pragma unroll
        for (int r = 0; r < 4; r++)
            lds[wave][q * 4 + r][col] = f2bf(leaky_f(acc[ct][r] + bv));
    }
    __syncthreads();

    if (lane < 32) {
        const int row = lane >> 1, o = lane & 1;
        float s = bo2[o];
        for (int k = 0; k < NH; k++)
            s += bf2f(lds[wave][row][k]) * Wo2[k * 2 + o];
        out[(size_t)(tile * 16 + row) * 2 + o] = s;
    }
}

extern "C" void kernel_launch(void* const* d_in, const int* in_sizes, int n_in,
                              void* d_out, int out_size, void* d_ws, size_t ws_size,
                              hipStream_t stream)
{
    const float* feat = (const float*)d_in[0];
    const int* ei   = (const int*)d_in[1];
    const int* et   = (const int*)d_in[2];
    const float* Wdes = (const float*)d_in[3];
    const float* bdes = (const float*)d_in[4];
    const float* Wtw  = (const float*)d_in[5];
    const float* btw  = (const float*)d_in[6];
    const float* Wnum = (const float*)d_in[7];
    const float* bnum = (const float*)d_in[8];
    const float* Wcat = (const float*)d_in[9];
    const float* bcat = (const float*)d_in[10];
    const float* Win  = (const float*)d_in[11];
    const float* bin  = (const float*)d_in[12];
    const float* rgW  = (const float*)d_in[13];
    const float* root = (const float*)d_in[14];
    const float* rbias= (const float*)d_in[15];
    const float* Wo1  = (const float*)d_in[16];
    const float* bo1  = (const float*)d_in[17];
    const float* Wo2  = (const float*)d_in[18];
    const float* bo2  = (const float*)d_in[19];
    const int* srcp = ei;
    const int* dstp = ei + NE;

    // Workspace carve (~212 MiB)
    char* p = (char*)d_ws;
    auto alloc = [&](size_t bytes) { char* r = p; p += (bytes + 255) & ~(size_t)255; return r; };
    unsigned short* xa = (unsigned short*)alloc((size_t)NN * NH * 2);
    unsigned short* xb = (unsigned short*)alloc((size_t)NN * NH * 2);
    int* deg  = (int*)alloc((size_t)NSEG * 4);
    int* offs = (int*)alloc((size_t)NSEG * 4);
    int* cur  = (int*)alloc((size_t)NSEG * 4);
    int* part = (int*)alloc((size_t)(SCAN_NB + 8) * 4);
    unsigned int* eidx = (unsigned int*)alloc((size_t)NE * 4);
    unsigned short* Benc = (unsigned short*)alloc((size_t)8 * KSENC * 512 * 2);
    unsigned short* sWin = (unsigned short*)alloc((size_t)8 * 4 * 512 * 2);
    unsigned short* Bxw  = (unsigned short*)alloc((size_t)CTXW * 4 * 512 * 2);
    unsigned short* sWo1 = (unsigned short*)alloc((size_t)8 * 4 * 512 * 2);
    float* be = (float*)alloc(128 * 4);
    unsigned short* xwbuf = (unsigned short*)alloc((size_t)NN * NRX * NH * 2);  // 166.4 MB

    const int GB = (MT + 3) / 4;            // 782 blocks of 4 waves
    const int GBXW = (MT2 * NRX + 3) / 4;   // 5080

    // CSR build
    hipMemsetAsync(deg, 0, (size_t)NSEG * 4, stream);
    hipMemsetAsync(cur, 0, (size_t)NSEG * 4, stream);
    hist_k<<<(NE + 255) / 256, 256, 0, stream>>>(dstp, et, deg);
    scanA_k<<<SCAN_NB, 256, 0, stream>>>(deg, offs, part);
    scanB_k<<<1, 256, 0, stream>>>(part, SCAN_NB);
    scanC_k<<<SCAN_NB, 256, 0, stream>>>(offs, part);
    fill_k<<<(NE + 255) / 256, 256, 0, stream>>>(srcp, dstp, et, offs, deg, cur, eidx);

    // Weight prep
    swzenc_k<<<(8 * KSENC * 512 + 255) / 256, 256, 0, stream>>>(Wdes, Wtw, Wnum, Wcat, Benc);
    packbias_k<<<1, 128, 0, stream>>>(bdes, btw, bnum, bcat, be);
    swz_k<<<(8 * 4 * 512 + 255) / 256, 256, 0, stream>>>(Win, 128, Win, 128, 128, 4, sWin);
    swzxw_k<<<(CTXW * 4 * 512 + 255) / 256, 256, 0, stream>>>(rgW, root, Bxw);
    swz_k<<<(8 * 4 * 512 + 255) / 256, 256, 0, stream>>>(Wo1, 128, Wo1, 128, 128, 4, sWo1);

    // Fused pipeline
    enc_k<<<GB, 256, 0, stream>>>(feat, Benc, be, sWin, bin, xa);
    // layer 1: transform-then-gather
    xw_k<<<GBXW, 256, 0, stream>>>(xa, Bxw, xwbuf);
    gather_k<<<GB, 256, 0, stream>>>(xwbuf, eidx, offs, rbias, xb);
    // layer 2
    xw_k<<<GBXW, 256, 0, stream>>>(xb, Bxw, xwbuf);
    gather_k<<<GB, 256, 0, stream>>>(xwbuf, eidx, offs, rbias, xa);
    head_k<<<GB, 256, 0, stream>>>(xa, sWo1, bo1, Wo2, bo2, (float*)d_out);
}

// Round 4
// 840.901 us; speedup vs baseline: 1.1156x; 1.0268x over previous
//
#include <hip/hip_runtime.h>
#include <stdint.h>

// Problem constants
#define NN 50000
#define NE 800000
#define NR 12
#define NRX 13                // 12 relations + root slot
#define NH 128
#define NF 1582
#define NSEG (NN * NR)        // 600000 (seg = d*12 + r)
#define MT 3125               // NN/16 row tiles (exact)
#define MT2 1563              // ceil(MT/2) for 32-row xw waves
#define SCAN_NB ((NSEG + 255) / 256)   // 2344
#define KSENC 50              // ceil(1582/32)
#define CTXW (NRX * 8)        // 104 col-tiles in stacked [128 x 13*128] weight

typedef __attribute__((ext_vector_type(8))) short short8;   // 8 x bf16
typedef __attribute__((ext_vector_type(4))) float floatx4;  // MFMA acc

__device__ __forceinline__ float bf2f(unsigned int u16) {
    union { unsigned int i; float f; } w; w.i = u16 << 16; return w.f;
}
__device__ __forceinline__ unsigned short f2bf(float f) {
    union { float f; unsigned int i; } w; w.f = f;
    unsigned int i = w.i;
    return (unsigned short)((i + 0x7FFFu + ((i >> 16) & 1u)) >> 16);  // RNE
}
__device__ __forceinline__ float leaky_f(float v) { return v > 0.f ? v : 0.01f * v; }
__device__ __forceinline__ float fast_rcp(float x) {
    float r; asm("v_rcp_f32 %0, %1" : "=v"(r) : "v"(x)); return r;
}

// ================= weight swizzles into MFMA B-fragment order =================
// layout: dst[((ct*KS+ks)*64+lane)*8 + j] = B[k][col], k=ks*32+(lane>>4)*8+j,
// col=ct*16+(lane&15). Zero outside valid k.
__global__ __launch_bounds__(256) void swz_k(
    const float* __restrict__ src1, int K1,
    const float* __restrict__ src2, int Ktot, int N, int KS,
    unsigned short* __restrict__ dst)
{
    const int idx = blockIdx.x * 256 + threadIdx.x;
    const int total = (N >> 4) * KS * 512;
    if (idx >= total) return;
    const int j = idx & 7;
    const int lane = (idx >> 3) & 63;
    const int cks = idx >> 9;
    const int ks = cks % KS;
    const int ct = cks / KS;
    const int k = ks * 32 + (lane >> 4) * 8 + j;
    const int col = ct * 16 + (lane & 15);
    float v = 0.f;
    if (k < Ktot) v = (k < K1) ? src1[(size_t)k * N + col] : src2[(size_t)(k - K1) * N + col];
    dst[idx] = f2bf(v);
}

// Per-relation weights stacked along COLUMNS: B[k][r*128+c] = rgW[r][k][c], r=12 -> root.
// Fragment layout matches xw_k's load: dst[((ctg*4+ks)*64+lane)*8+j], ctg = r*8+ct8.
__global__ __launch_bounds__(256) void swzxw_k(
    const float* __restrict__ rgW, const float* __restrict__ root,
    unsigned short* __restrict__ dst)
{
    const int idx = blockIdx.x * 256 + threadIdx.x;
    const int total = CTXW * 4 * 512;   // 212992
    if (idx >= total) return;
    const int j = idx & 7;
    const int lane = (idx >> 3) & 63;
    const int cks = idx >> 9;
    const int ks = cks & 3;
    const int ctg = cks >> 2;           // 0..103
    const int r = ctg >> 3;             // 0..12
    const int ct8 = ctg & 7;
    const int k = ks * 32 + (lane >> 4) * 8 + j;
    const int c = ct8 * 16 + (lane & 15);
    const float v = (r < NR) ? rgW[((size_t)r * NH + k) * NH + c]
                             : root[(size_t)k * NH + c];
    dst[idx] = f2bf(v);
}

// Encoder block-diagonal B [1582(pad 1600) x 128]:
// cols 0..31: Wdes rows 46..814 | 32..63: Wtw rows 814..1582
// cols 64..95: Wnum rows 12..46 | 96..127: Wcat rows 0..12
__global__ __launch_bounds__(256) void swzenc_k(
    const float* __restrict__ Wdes, const float* __restrict__ Wtw,
    const float* __restrict__ Wnum, const float* __restrict__ Wcat,
    unsigned short* __restrict__ dst)
{
    const int idx = blockIdx.x * 256 + threadIdx.x;
    const int total = 8 * KSENC * 512;
    if (idx >= total) return;
    const int j = idx & 7;
    const int lane = (idx >> 3) & 63;
    const int cks = idx >> 9;
    const int ks = cks % KSENC;
    const int ct = cks / KSENC;
    const int k = ks * 32 + (lane >> 4) * 8 + j;
    const int col = ct * 16 + (lane & 15);
    float v = 0.f;
    if (col < 32) {
        if (k >= 46 && k < 814)   v = Wdes[(size_t)(k - 46) * 32 + col];
    } else if (col < 64) {
        if (k >= 814 && k < 1582) v = Wtw[(size_t)(k - 814) * 32 + (col - 32)];
    } else if (col < 96) {
        if (k >= 12 && k < 46)    v = Wnum[(size_t)(k - 12) * 32 + (col - 64)];
    } else {
        if (k < 12)               v = Wcat[(size_t)k * 32 + (col - 96)];
    }
    dst[idx] = f2bf(v);
}

__global__ __launch_bounds__(128) void packbias_k(
    const float* __restrict__ bdes, const float* __restrict__ btw,
    const float* __restrict__ bnum, const float* __restrict__ bcat,
    float* __restrict__ be)
{
    const int c = threadIdx.x;
    float v;
    if (c < 32) v = bdes[c];
    else if (c < 64) v = btw[c - 32];
    else if (c < 96) v = bnum[c - 64];
    else v = bcat[c - 96];
    be[c] = v;
}

// ================= CSR build =================
__global__ __launch_bounds__(256) void hist_k(const int* __restrict__ dst,
                                              const int* __restrict__ et,
                                              int* __restrict__ deg)
{
    const int e = blockIdx.x * 256 + threadIdx.x;
    if (e >= NE) return;
    atomicAdd(&deg[dst[e] * NR + et[e]], 1);
}

__global__ __launch_bounds__(256) void scanA_k(const int* __restrict__ deg,
                                               int* __restrict__ offs,
                                               int* __restrict__ part)
{
    __shared__ int lds[256];
    const int i = blockIdx.x * 256 + threadIdx.x;
    const int v = (i < NSEG) ? deg[i] : 0;
    lds[threadIdx.x] = v; __syncthreads();
#pragma unroll
    for (int d = 1; d < 256; d <<= 1) {
        const int t = (threadIdx.x >= d) ? lds[threadIdx.x - d] : 0;
        __syncthreads();
        lds[threadIdx.x] += t;
        __syncthreads();
    }
    if (i < NSEG) offs[i] = lds[threadIdx.x] - v;
    if (threadIdx.x == 255) part[blockIdx.x] = lds[255];
}

__global__ __launch_bounds__(256) void scanB_k(int* __restrict__ part, int nb)
{
    __shared__ int lds[256];
    __shared__ int carry;
    if (threadIdx.x == 0) carry = 0;
    __syncthreads();
    for (int base = 0; base < nb; base += 256) {
        const int i = base + threadIdx.x;
        const int v = (i < nb) ? part[i] : 0;
        lds[threadIdx.x] = v; __syncthreads();
#pragma unroll
        for (int d = 1; d < 256; d <<= 1) {
            const int t = (threadIdx.x >= d) ? lds[threadIdx.x - d] : 0;
            __syncthreads();
            lds[threadIdx.x] += t;
            __syncthreads();
        }
        if (i < nb) part[i] = lds[threadIdx.x] - v + carry;
        __syncthreads();
        if (threadIdx.x == 255) carry += lds[255];
        __syncthreads();
    }
}

__global__ __launch_bounds__(256) void scanC_k(int* __restrict__ offs,
                                               const int* __restrict__ part)
{
    const int i = blockIdx.x * 256 + threadIdx.x;
    if (i < NSEG) offs[i] += part[blockIdx.x];
}

// pack (xw row index = src*13 + r) | deg<<20 so the gather loop is uniform over r
__global__ __launch_bounds__(256) void fill_k(const int* __restrict__ src,
                                              const int* __restrict__ dst,
                                              const int* __restrict__ et,
                                              const int* __restrict__ offs,
                                              const int* __restrict__ deg,
                                              int* __restrict__ cur,
                                              unsigned int* __restrict__ eidx)
{
    const int e = blockIdx.x * 256 + threadIdx.x;
    if (e >= NE) return;
    const int r = et[e];
    const int s = dst[e] * NR + r;
    const int pos = offs[s] + atomicAdd(&cur[s], 1);
    int n = deg[s]; if (n > 4095) n = 4095;
    eidx[pos] = (unsigned int)(src[e] * NRX + r) | ((unsigned int)n << 20);
}

// ================= fused encoder: feat -> blockdiag GEMM -> leaky -> W_in -> xa ===========
__global__ __launch_bounds__(256) void enc_k(
    const float* __restrict__ feat,
    const unsigned short* __restrict__ Benc, const float* __restrict__ be,
    const unsigned short* __restrict__ Bwin, const float* __restrict__ bin,
    unsigned short* __restrict__ xa)
{
    const int wave = threadIdx.x >> 6, lane = threadIdx.x & 63;
    const int q = lane >> 4, cl = lane & 15;
    int tile = blockIdx.x * 4 + wave;
    if (tile >= MT) tile = MT - 1;          // duplicate work; identical stores (benign)
    const int row = tile * 16 + cl;

    // active ks ranges per col-tile: des[46,814) tw[814,1582) num[12,46) cat[0,12)
    const int lo[8] = {1, 1, 25, 25, 0, 0, 0, 0};
    const int hi[8] = {26, 26, 50, 50, 2, 2, 1, 1};

    floatx4 acc[8];
#pragma unroll
    for (int ct = 0; ct < 8; ct++) { floatx4 z = {0.f,0.f,0.f,0.f}; acc[ct] = z; }

    for (int ks = 0; ks < KSENC; ks++) {
        const int kb = ks * 32 + q * 8;
        union { short8 v; unsigned short u[8]; } a;
        const float* ap = feat + (size_t)row * NF + kb;
        if (kb + 7 < NF) {
#pragma unroll
            for (int j = 0; j < 4; j++) {
                const float2 t = *(const float2*)__builtin_assume_aligned(ap + 2 * j, 8);
                a.u[2 * j]     = f2bf(t.x);
                a.u[2 * j + 1] = f2bf(t.y);
            }
        } else {
#pragma unroll
            for (int j = 0; j < 8; j++)
                a.u[j] = ((kb + j) < NF) ? f2bf(ap[j]) : 0;
        }
#pragma unroll
        for (int ct = 0; ct < 8; ct++) {
            if (ks >= lo[ct] && ks < hi[ct]) {
                const short8 b = *(const short8*)(Benc + ((size_t)(ct * KSENC + ks) * 64 + lane) * 8);
                acc[ct] = __builtin_amdgcn_mfma_f32_16x16x32_bf16(a.v, b, acc[ct], 0, 0, 0);
            }
        }
    }

    // leaky(acc + bias) -> LDS tile (C-layout -> A-layout transpose)
    __shared__ unsigned short lds[4][16][136];   // +8 pad: 2-way banks only
#pragma unroll
    for (int ct = 0; ct < 8; ct++) {
        const int col = ct * 16 + cl;
        const float bv = be[col];
#pragma unroll
        for (int r = 0; r < 4; r++)
            lds[wave][q * 4 + r][col] = f2bf(leaky_f(acc[ct][r] + bv));
    }
    __syncthreads();   // all 256 threads active (tile clamped)

    // W_in stage: A from LDS
    floatx4 acc2[8];
#pragma unroll
    for (int ct = 0; ct < 8; ct++) { floatx4 z = {0.f,0.f,0.f,0.f}; acc2[ct] = z; }
#pragma unroll
    for (int ks2 = 0; ks2 < 4; ks2++) {
        const short8 a2 = *(const short8*)&lds[wave][cl][ks2 * 32 + q * 8];
#pragma unroll
        for (int ct = 0; ct < 8; ct++) {
            const short8 b = *(const short8*)(Bwin + ((size_t)(ct * 4 + ks2) * 64 + lane) * 8);
            acc2[ct] = __builtin_amdgcn_mfma_f32_16x16x32_bf16(a2, b, acc2[ct], 0, 0, 0);
        }
    }
#pragma unroll
    for (int ct = 0; ct < 8; ct++) {
        const int col = ct * 16 + cl;
        const float bv = bin[col];
#pragma unroll
        for (int r = 0; r < 4; r++)
            xa[(size_t)(tile * 16 + q * 4 + r) * NH + col] = f2bf(leaky_f(acc2[ct][r] + bv));
    }
}

// ============ RGCN layer, stage 1: xw[n, r, :] = x[n] @ W_r  (r=12 -> root) ============
// 32 rows per wave; LDS transpose (with barrier) so the 166MB output is written as
// 16B short8 stores (8 insts/lane) instead of 64 scalar 2B stores.
__global__ __launch_bounds__(256) void xw_k(
    const unsigned short* __restrict__ xin,
    const unsigned short* __restrict__ Bxw,
    unsigned short* __restrict__ xw)
{
    const int wave = threadIdx.x >> 6, lane = threadIdx.x & 63;
    const int q = lane >> 4, cl = lane & 15;
    int wid = blockIdx.x * 4 + wave;
    if (wid >= MT2 * NRX) wid = MT2 * NRX - 1;   // clamp: duplicate identical stores
    __shared__ unsigned short tl[4][2][16][136];
    const int t2 = wid / NRX;
    const int r = wid - t2 * NRX;
    const int ta = t2 * 2;
    const int tb = (ta + 1 < MT) ? ta + 1 : MT - 1;   // clamp: duplicate identical stores

    floatx4 accA[8], accB[8];
#pragma unroll
    for (int ct = 0; ct < 8; ct++) {
        floatx4 z = {0.f,0.f,0.f,0.f}; accA[ct] = z; accB[ct] = z;
    }
#pragma unroll
    for (int ks = 0; ks < 4; ks++) {
        const short8 aA = *(const short8*)__builtin_assume_aligned(
            xin + (size_t)(ta * 16 + cl) * NH + ks * 32 + q * 8, 16);
        const short8 aB = *(const short8*)__builtin_assume_aligned(
            xin + (size_t)(tb * 16 + cl) * NH + ks * 32 + q * 8, 16);
#pragma unroll
        for (int ct = 0; ct < 8; ct++) {
            const short8 b = *(const short8*)(Bxw + ((size_t)((r * 8 + ct) * 4 + ks) * 64 + lane) * 8);
            accA[ct] = __builtin_amdgcn_mfma_f32_16x16x32_bf16(aA, b, accA[ct], 0, 0, 0);
            accB[ct] = __builtin_amdgcn_mfma_f32_16x16x32_bf16(aB, b, accB[ct], 0, 0, 0);
        }
    }
    // C-frag -> LDS (row-major bf16)
#pragma unroll
    for (int ct = 0; ct < 8; ct++) {
        const int col = ct * 16 + cl;
#pragma unroll
        for (int rr = 0; rr < 4; rr++) {
            tl[wave][0][q * 4 + rr][col] = f2bf(accA[ct][rr]);
            tl[wave][1][q * 4 + rr][col] = f2bf(accB[ct][rr]);
        }
    }
    __syncthreads();   // all 256 threads active (wid clamped) — orders LDS write->read
    // read back row-major, 16B stores: per inst 16 lanes cover a full 256B row
#pragma unroll
    for (int i = 0; i < 4; i++) {
        const int row = i * 4 + q;
        const short8 vA = *(const short8*)&tl[wave][0][row][cl * 8];
        const short8 vB = *(const short8*)&tl[wave][1][row][cl * 8];
        *(short8*)(xw + ((size_t)(ta * 16 + row) * NRX + r) * NH + cl * 8) = vA;
        *(short8*)(xw + ((size_t)(tb * 16 + row) * NRX + r) * NH + cl * 8) = vB;
    }
}

// ============ RGCN layer, stage 2: uniform per-node gather-sum of transformed rows ======
// out[d] = sum_{e in edges(d)} (1/n_e) * xw[src_e, r_e]  +  xw[d, 12]  + bias
// 2 waves per 16-node tile; each lane owns TWO 16B col chunks: cA=half*8+q, cB=cA+4
// -> chunks 0..15 cover all 128 cols (16 nodes x 128 cols = 2048 = 128 lanes x 16 cols).
// Edge loop unrolled x2 with independent (affine) index loads -> no dep chain.
// NOTE: macro params must not collide with vector field names x/y/z/w!
#define ACC8(fk, tv, wv) \
    fk[0] += (wv) * bf2f((tv).x & 0xFFFFu); fk[1] += (wv) * bf2f((tv).x >> 16); \
    fk[2] += (wv) * bf2f((tv).y & 0xFFFFu); fk[3] += (wv) * bf2f((tv).y >> 16); \
    fk[4] += (wv) * bf2f((tv).z & 0xFFFFu); fk[5] += (wv) * bf2f((tv).z >> 16); \
    fk[6] += (wv) * bf2f((tv).w & 0xFFFFu); fk[7] += (wv) * bf2f((tv).w >> 16);

#define INIT8(fk, tv) \
    fk[0] = bf2f((tv).x & 0xFFFFu); fk[1] = bf2f((tv).x >> 16); \
    fk[2] = bf2f((tv).y & 0xFFFFu); fk[3] = bf2f((tv).y >> 16); \
    fk[4] = bf2f((tv).z & 0xFFFFu); fk[5] = bf2f((tv).z >> 16); \
    fk[6] = bf2f((tv).w & 0xFFFFu); fk[7] = bf2f((tv).w >> 16);

__global__ __launch_bounds__(256) void gather_k(
    const unsigned short* __restrict__ xw,
    const unsigned int* __restrict__ eidx,
    const int* __restrict__ offs,
    const float* __restrict__ rbias,
    unsigned short* __restrict__ xout)
{
    const int wave = threadIdx.x >> 6, lane = threadIdx.x & 63;
    const int q = lane >> 4, cl = lane & 15;
    const int wid = blockIdx.x * 4 + wave;
    const int tile = wid >> 1;
    if (tile >= MT) return;                  // no LDS/barrier in this kernel
    const int half = wid & 1;
    const int cA = half * 8 + q;             // 16B col chunk 0..15
    const int cB = cA + 4;
    const int d = tile * 16 + cl;
    const int beg = offs[d * NR];
    const int end = (d < NN - 1) ? offs[(d + 1) * NR] : NE;

    float fA[8], fB[8];
    {   // root contribution, weight 1
        const unsigned short* xr = xw + ((size_t)d * NRX + NR) * NH;
        const uint4 tA = *(const uint4*)(xr + cA * 8);
        const uint4 tB = *(const uint4*)(xr + cB * 8);
        INIT8(fA, tA); INIT8(fB, tB);
    }

    for (int e = beg; e < end; e += 2) {
        const int e1 = (e + 1 < end) ? e + 1 : e;
        const unsigned int v0 = eidx[e];
        const unsigned int v1 = eidx[e1];
        const float w0 = fast_rcp((float)(v0 >> 20));
        const float w1 = (e + 1 < end) ? fast_rcp((float)(v1 >> 20)) : 0.f;
        const unsigned short* x0 = xw + (size_t)(v0 & 0xFFFFFu) * NH;
        const unsigned short* x1 = xw + (size_t)(v1 & 0xFFFFFu) * NH;
        const uint4 a0 = *(const uint4*)(x0 + cA * 8);
        const uint4 b0 = *(const uint4*)(x0 + cB * 8);
        const uint4 a1 = *(const uint4*)(x1 + cA * 8);
        const uint4 b1 = *(const uint4*)(x1 + cB * 8);
        ACC8(fA, a0, w0); ACC8(fB, b0, w0);
        ACC8(fA, a1, w1); ACC8(fB, b1, w1);
    }

    union { short8 v; unsigned short u[8]; } oA, oB;
#pragma unroll
    for (int m = 0; m < 8; m++) {
        oA.u[m] = f2bf(fA[m] + rbias[cA * 8 + m]);
        oB.u[m] = f2bf(fB[m] + rbias[cB * 8 + m]);
    }
    *(short8*)(xout + (size_t)d * NH + cA * 8) = oA.v;
    *(short8*)(xout + (size_t)d * NH + cB * 8) = oB.v;
}

// ============ fused head: leaky(xa@Wo1+b) then @Wo2+b2 -> out ============
__global__ __launch_bounds__(256) void head_k(
    const unsigned short* __restrict__ xa,
    const unsigned short* __restrict__ Bo1, const float* __restrict__ bo1,
    const float* __restrict__ Wo2, const float* __restrict__ bo2,
    float* __restrict__ out)
{
    const int wave = threadIdx.x >> 6, lane = threadIdx.x & 63;
    const int q = lane >> 4, cl = lane & 15;
    int tile = blockIdx.x * 4 + wave;
    if (tile >= MT) tile = MT - 1;           // clamp; duplicate identical stores

    floatx4 acc[8];
#pragma unroll
    for (int ct = 0; ct < 8; ct++) { floatx4 z = {0.f,0.f,0.f,0.f}; acc[ct] = z; }
#pragma unroll
    for (int ks = 0; ks < 4; ks++) {
        const short8 a = *(const short8*)__builtin_assume_aligned(
            xa + (size_t)(tile * 16 + cl) * NH + ks * 32 + q * 8, 16);
#pragma unroll
        for (int ct = 0; ct < 8; ct++) {
            const short8 b = *(const short8*)(Bo1 + ((size_t)(ct * 4 + ks) * 64 + lane) * 8);
            acc[ct] = __builtin_amdgcn_mfma_f32_16x16x32_bf16(a, b, acc[ct], 0, 0, 0);
        }
    }
    __shared__ unsigned short lds[4][16][136];
#pragma unroll
    for (int ct = 0; ct < 8; ct++) {
        const int col = ct * 16 + cl;
        const float bv = bo1[col];
#pragma unroll
        for (int r = 0; r < 4; r++)
            lds[wave][q * 4 + r][col] = f2bf(leaky_f(acc[ct][r] + bv));
    }
    __syncthreads();

    if (lane < 32) {
        const int row = lane >> 1, o = lane & 1;
        float s = bo2[o];
        for (int k = 0; k < NH; k++)
            s += bf2f(lds[wave][row][k]) * Wo2[k * 2 + o];
        out[(size_t)(tile * 16 + row) * 2 + o] = s;
    }
}

extern "C" void kernel_launch(void* const* d_in, const int* in_sizes, int n_in,
                              void* d_out, int out_size, void* d_ws, size_t ws_size,
                              hipStream_t stream)
{
    const float* feat = (const float*)d_in[0];
    const int* ei   = (const int*)d_in[1];
    const int* et   = (const int*)d_in[2];
    const float* Wdes = (const float*)d_in[3];
    const float* bdes = (const float*)d_in[4];
    const float* Wtw  = (const float*)d_in[5];
    const float* btw  = (const float*)d_in[6];
    const float* Wnum = (const float*)d_in[7];
    const float* bnum = (const float*)d_in[8];
    const float* Wcat = (const float*)d_in[9];
    const float* bcat = (const float*)d_in[10];
    const float* Win  = (const float*)d_in[11];
    const float* bin  = (const float*)d_in[12];
    const float* rgW  = (const float*)d_in[13];
    const float* root = (const float*)d_in[14];
    const float* rbias= (const float*)d_in[15];
    const float* Wo1  = (const float*)d_in[16];
    const float* bo1  = (const float*)d_in[17];
    const float* Wo2  = (const float*)d_in[18];
    const float* bo2  = (const float*)d_in[19];
    const int* srcp = ei;
    const int* dstp = ei + NE;

    // Workspace carve (~212 MiB)
    char* p = (char*)d_ws;
    auto alloc = [&](size_t bytes) { char* r = p; p += (bytes + 255) & ~(size_t)255; return r; };
    unsigned short* xa = (unsigned short*)alloc((size_t)NN * NH * 2);
    unsigned short* xb = (unsigned short*)alloc((size_t)NN * NH * 2);
    int* deg  = (int*)alloc((size_t)NSEG * 4);
    int* offs = (int*)alloc((size_t)NSEG * 4);
    int* cur  = (int*)alloc((size_t)NSEG * 4);
    int* part = (int*)alloc((size_t)(SCAN_NB + 8) * 4);
    unsigned int* eidx = (unsigned int*)alloc((size_t)NE * 4);
    unsigned short* Benc = (unsigned short*)alloc((size_t)8 * KSENC * 512 * 2);
    unsigned short* sWin = (unsigned short*)alloc((size_t)8 * 4 * 512 * 2);
    unsigned short* Bxw  = (unsigned short*)alloc((size_t)CTXW * 4 * 512 * 2);
    unsigned short* sWo1 = (unsigned short*)alloc((size_t)8 * 4 * 512 * 2);
    float* be = (float*)alloc(128 * 4);
    unsigned short* xwbuf = (unsigned short*)alloc((size_t)NN * NRX * NH * 2);  // 166.4 MB

    const int GB = (MT + 3) / 4;            // 782 blocks of 4 waves
    const int GBXW = (MT2 * NRX + 3) / 4;   // 5080
    const int GB2 = (MT * 2 + 3) / 4;       // 1563 (gather: 2 waves/tile)

    // CSR build
    hipMemsetAsync(deg, 0, (size_t)NSEG * 4, stream);
    hipMemsetAsync(cur, 0, (size_t)NSEG * 4, stream);
    hist_k<<<(NE + 255) / 256, 256, 0, stream>>>(dstp, et, deg);
    scanA_k<<<SCAN_NB, 256, 0, stream>>>(deg, offs, part);
    scanB_k<<<1, 256, 0, stream>>>(part, SCAN_NB);
    scanC_k<<<SCAN_NB, 256, 0, stream>>>(offs, part);
    fill_k<<<(NE + 255) / 256, 256, 0, stream>>>(srcp, dstp, et, offs, deg, cur, eidx);

    // Weight prep
    swzenc_k<<<(8 * KSENC * 512 + 255) / 256, 256, 0, stream>>>(Wdes, Wtw, Wnum, Wcat, Benc);
    packbias_k<<<1, 128, 0, stream>>>(bdes, btw, bnum, bcat, be);
    swz_k<<<(8 * 4 * 512 + 255) / 256, 256, 0, stream>>>(Win, 128, Win, 128, 128, 4, sWin);
    swzxw_k<<<(CTXW * 4 * 512 + 255) / 256, 256, 0, stream>>>(rgW, root, Bxw);
    swz_k<<<(8 * 4 * 512 + 255) / 256, 256, 0, stream>>>(Wo1, 128, Wo1, 128, 128, 4, sWo1);

    // Fused pipeline
    enc_k<<<GB, 256, 0, stream>>>(feat, Benc, be, sWin, bin, xa);
    // layer 1: transform-then-gather
    xw_k<<<GBXW, 256, 0, stream>>>(xa, Bxw, xwbuf);
    gather_k<<<GB2, 256, 0, stream>>>(xwbuf, eidx, offs, rbias, xb);
    // layer 2
    xw_k<<<GBXW, 256, 0, stream>>>(xb, Bxw, xwbuf);
    gather_k<<<GB2, 256, 0, stream>>>(xwbuf, eidx, offs, rbias, xa);
    head_k<<<GB, 256, 0, stream>>>(xa, sWo1, bo1, Wo2, bo2, (float*)d_out);
}

// Round 5
// 825.404 us; speedup vs baseline: 1.1366x; 1.0188x over previous
//
#include <hip/hip_runtime.h>
#include <stdint.h>

// Problem constants
#define NN 50000
#define NE 800000
#define NR 12
#define NRX 13                // 12 relations + root slot
#define NH 128
#define NF 1582
#define NSEG (NN * NR)        // 600000 (seg = d*12 + r)
#define MT 3125               // NN/16 row tiles (exact)
#define MT2 1563              // ceil(MT/2) for 32-row xw waves
#define SCAN_NB ((NSEG + 255) / 256)   // 2344
#define KSENC 50              // ceil(1582/32)
#define CTXW (NRX * 8)        // 104 col-tiles in stacked [128 x 13*128] weight
#define TOTENC (8 * KSENC * 512)       // 204800
#define TOT128 (8 * 4 * 512)           // 16384
#define TOTXW  (CTXW * 4 * 512)        // 212992
#define TOTPREP (TOTENC + TOT128 + TOTXW + TOT128 + 128)

typedef __attribute__((ext_vector_type(8))) short short8;   // 8 x bf16
typedef __attribute__((ext_vector_type(4))) float floatx4;  // MFMA acc

__device__ __forceinline__ float bf2f(unsigned int u16) {
    union { unsigned int i; float f; } w; w.i = u16 << 16; return w.f;
}
__device__ __forceinline__ unsigned short f2bf(float f) {
    union { float f; unsigned int i; } w; w.f = f;
    unsigned int i = w.i;
    return (unsigned short)((i + 0x7FFFu + ((i >> 16) & 1u)) >> 16);  // RNE
}
__device__ __forceinline__ float leaky_f(float v) { return v > 0.f ? v : 0.01f * v; }
__device__ __forceinline__ float fast_rcp(float x) {
    float r; asm("v_rcp_f32 %0, %1" : "=v"(r) : "v"(x)); return r;
}

// ================= single merged weight-prep kernel =================
// Fragment layout (all tables): dst[((ct*KS+ks)*64+lane)*8 + j] = B[k][col],
// k=ks*32+(lane>>4)*8+j, col=ct*16+(lane&15).
// Ranges: [0,TOTENC) Benc | [,+TOT128) sWin | [,+TOTXW) Bxw | [,+TOT128) sWo1 | [,+128) be
__global__ __launch_bounds__(256) void prep_k(
    const float* __restrict__ Wdes, const float* __restrict__ Wtw,
    const float* __restrict__ Wnum, const float* __restrict__ Wcat,
    const float* __restrict__ Win,  const float* __restrict__ rgW,
    const float* __restrict__ root, const float* __restrict__ Wo1,
    const float* __restrict__ bdes, const float* __restrict__ btw,
    const float* __restrict__ bnum, const float* __restrict__ bcat,
    unsigned short* __restrict__ Benc, unsigned short* __restrict__ sWin,
    unsigned short* __restrict__ Bxw,  unsigned short* __restrict__ sWo1,
    float* __restrict__ be)
{
    int idx = blockIdx.x * 256 + threadIdx.x;
    if (idx < TOTENC) {
        // encoder block-diagonal B [1582(pad 1600) x 128]
        const int j = idx & 7;
        const int lane = (idx >> 3) & 63;
        const int cks = idx >> 9;
        const int ks = cks % KSENC;
        const int ct = cks / KSENC;
        const int k = ks * 32 + (lane >> 4) * 8 + j;
        const int col = ct * 16 + (lane & 15);
        float v = 0.f;
        if (col < 32) {
            if (k >= 46 && k < 814)   v = Wdes[(size_t)(k - 46) * 32 + col];
        } else if (col < 64) {
            if (k >= 814 && k < 1582) v = Wtw[(size_t)(k - 814) * 32 + (col - 32)];
        } else if (col < 96) {
            if (k >= 12 && k < 46)    v = Wnum[(size_t)(k - 12) * 32 + (col - 64)];
        } else {
            if (k < 12)               v = Wcat[(size_t)k * 32 + (col - 96)];
        }
        Benc[idx] = f2bf(v);
        return;
    }
    idx -= TOTENC;
    if (idx < TOT128) {        // W_in [128x128], KS=4
        const int j = idx & 7;
        const int lane = (idx >> 3) & 63;
        const int cks = idx >> 9;
        const int ks = cks & 3;
        const int ct = cks >> 2;
        const int k = ks * 32 + (lane >> 4) * 8 + j;
        const int col = ct * 16 + (lane & 15);
        sWin[idx] = f2bf(Win[(size_t)k * NH + col]);
        return;
    }
    idx -= TOT128;
    if (idx < TOTXW) {         // stacked rgcn W (12 rel + root), ctg = r*8+ct8
        const int j = idx & 7;
        const int lane = (idx >> 3) & 63;
        const int cks = idx >> 9;
        const int ks = cks & 3;
        const int ctg = cks >> 2;           // 0..103
        const int r = ctg >> 3;             // 0..12
        const int ct8 = ctg & 7;
        const int k = ks * 32 + (lane >> 4) * 8 + j;
        const int c = ct8 * 16 + (lane & 15);
        const float v = (r < NR) ? rgW[((size_t)r * NH + k) * NH + c]
                                 : root[(size_t)k * NH + c];
        Bxw[idx] = f2bf(v);
        return;
    }
    idx -= TOTXW;
    if (idx < TOT128) {        // W_out1 [128x128], KS=4
        const int j = idx & 7;
        const int lane = (idx >> 3) & 63;
        const int cks = idx >> 9;
        const int ks = cks & 3;
        const int ct = cks >> 2;
        const int k = ks * 32 + (lane >> 4) * 8 + j;
        const int col = ct * 16 + (lane & 15);
        sWo1[idx] = f2bf(Wo1[(size_t)k * NH + col]);
        return;
    }
    idx -= TOT128;
    if (idx < 128) {           // packed encoder bias
        const int c = idx;
        float v;
        if (c < 32) v = bdes[c];
        else if (c < 64) v = btw[c - 32];
        else if (c < 96) v = bnum[c - 64];
        else v = bcat[c - 96];
        be[c] = v;
    }
}

// ================= CSR build =================
__global__ __launch_bounds__(256) void zero_k(int* __restrict__ deg,
                                              int* __restrict__ cur)
{
    const int i = blockIdx.x * 256 + threadIdx.x;
    if (i < NSEG) { deg[i] = 0; cur[i] = 0; }
}

__global__ __launch_bounds__(256) void hist_k(const int* __restrict__ dst,
                                              const int* __restrict__ et,
                                              int* __restrict__ deg)
{
    const int e = blockIdx.x * 256 + threadIdx.x;
    if (e >= NE) return;
    atomicAdd(&deg[dst[e] * NR + et[e]], 1);
}

__global__ __launch_bounds__(256) void scanA_k(const int* __restrict__ deg,
                                               int* __restrict__ offs,
                                               int* __restrict__ part)
{
    __shared__ int lds[256];
    const int i = blockIdx.x * 256 + threadIdx.x;
    const int v = (i < NSEG) ? deg[i] : 0;
    lds[threadIdx.x] = v; __syncthreads();
#pragma unroll
    for (int d = 1; d < 256; d <<= 1) {
        const int t = (threadIdx.x >= d) ? lds[threadIdx.x - d] : 0;
        __syncthreads();
        lds[threadIdx.x] += t;
        __syncthreads();
    }
    if (i < NSEG) offs[i] = lds[threadIdx.x] - v;
    if (threadIdx.x == 255) part[blockIdx.x] = lds[255];
}

__global__ __launch_bounds__(256) void scanB_k(int* __restrict__ part, int nb)
{
    __shared__ int lds[256];
    __shared__ int carry;
    if (threadIdx.x == 0) carry = 0;
    __syncthreads();
    for (int base = 0; base < nb; base += 256) {
        const int i = base + threadIdx.x;
        const int v = (i < nb) ? part[i] : 0;
        lds[threadIdx.x] = v; __syncthreads();
#pragma unroll
        for (int d = 1; d < 256; d <<= 1) {
            const int t = (threadIdx.x >= d) ? lds[threadIdx.x - d] : 0;
            __syncthreads();
            lds[threadIdx.x] += t;
            __syncthreads();
        }
        if (i < nb) part[i] = lds[threadIdx.x] - v + carry;
        __syncthreads();
        if (threadIdx.x == 255) carry += lds[255];
        __syncthreads();
    }
}

// pack (xw row index = src*13 + r) | deg<<20 so the gather loop is uniform over r.
// Global offset = offs[s] + part[s>>8] (scanC folded into consumers).
__global__ __launch_bounds__(256) void fill_k(const int* __restrict__ src,
                                              const int* __restrict__ dst,
                                              const int* __restrict__ et,
                                              const int* __restrict__ offs,
                                              const int* __restrict__ part,
                                              const int* __restrict__ deg,
                                              int* __restrict__ cur,
                                              unsigned int* __restrict__ eidx)
{
    const int e = blockIdx.x * 256 + threadIdx.x;
    if (e >= NE) return;
    const int r = et[e];
    const int s = dst[e] * NR + r;
    const int pos = offs[s] + part[s >> 8] + atomicAdd(&cur[s], 1);
    int n = deg[s]; if (n > 4095) n = 4095;
    eidx[pos] = (unsigned int)(src[e] * NRX + r) | ((unsigned int)n << 20);
}

// ================= fused encoder: feat -> blockdiag GEMM -> leaky -> W_in -> xa ===========
__global__ __launch_bounds__(256) void enc_k(
    const float* __restrict__ feat,
    const unsigned short* __restrict__ Benc, const float* __restrict__ be,
    const unsigned short* __restrict__ Bwin, const float* __restrict__ bin,
    unsigned short* __restrict__ xa)
{
    const int wave = threadIdx.x >> 6, lane = threadIdx.x & 63;
    const int q = lane >> 4, cl = lane & 15;
    int tile = blockIdx.x * 4 + wave;
    if (tile >= MT) tile = MT - 1;          // duplicate work; identical stores (benign)
    const int row = tile * 16 + cl;

    // active ks ranges per col-tile: des[46,814) tw[814,1582) num[12,46) cat[0,12)
    const int lo[8] = {1, 1, 25, 25, 0, 0, 0, 0};
    const int hi[8] = {26, 26, 50, 50, 2, 2, 1, 1};

    floatx4 acc[8];
#pragma unroll
    for (int ct = 0; ct < 8; ct++) { floatx4 z = {0.f,0.f,0.f,0.f}; acc[ct] = z; }

    for (int ks = 0; ks < KSENC; ks++) {
        const int kb = ks * 32 + q * 8;
        union { short8 v; unsigned short u[8]; } a;
        const float* ap = feat + (size_t)row * NF + kb;
        if (kb + 7 < NF) {
#pragma unroll
            for (int j = 0; j < 4; j++) {
                const float2 t = *(const float2*)__builtin_assume_aligned(ap + 2 * j, 8);
                a.u[2 * j]     = f2bf(t.x);
                a.u[2 * j + 1] = f2bf(t.y);
            }
        } else {
#pragma unroll
            for (int j = 0; j < 8; j++)
                a.u[j] = ((kb + j) < NF) ? f2bf(ap[j]) : 0;
        }
#pragma unroll
        for (int ct = 0; ct < 8; ct++) {
            if (ks >= lo[ct] && ks < hi[ct]) {
                const short8 b = *(const short8*)(Benc + ((size_t)(ct * KSENC + ks) * 64 + lane) * 8);
                acc[ct] = __builtin_amdgcn_mfma_f32_16x16x32_bf16(a.v, b, acc[ct], 0, 0, 0);
            }
        }
    }

    // leaky(acc + bias) -> LDS tile (C-layout -> A-layout transpose)
    __shared__ unsigned short lds[4][16][136];   // +8 pad: 2-way banks only
#pragma unroll
    for (int ct = 0; ct < 8; ct++) {
        const int col = ct * 16 + cl;
        const float bv = be[col];
#pragma unroll
        for (int r = 0; r < 4; r++)
            lds[wave][q * 4 + r][col] = f2bf(leaky_f(acc[ct][r] + bv));
    }
    __syncthreads();   // all 256 threads active (tile clamped)

    // W_in stage: A from LDS
    floatx4 acc2[8];
#pragma unroll
    for (int ct = 0; ct < 8; ct++) { floatx4 z = {0.f,0.f,0.f,0.f}; acc2[ct] = z; }
#pragma unroll
    for (int ks2 = 0; ks2 < 4; ks2++) {
        const short8 a2 = *(const short8*)&lds[wave][cl][ks2 * 32 + q * 8];
#pragma unroll
        for (int ct = 0; ct < 8; ct++) {
            const short8 b = *(const short8*)(Bwin + ((size_t)(ct * 4 + ks2) * 64 + lane) * 8);
            acc2[ct] = __builtin_amdgcn_mfma_f32_16x16x32_bf16(a2, b, acc2[ct], 0, 0, 0);
        }
    }
#pragma unroll
    for (int ct = 0; ct < 8; ct++) {
        const int col = ct * 16 + cl;
        const float bv = bin[col];
#pragma unroll
        for (int r = 0; r < 4; r++)
            xa[(size_t)(tile * 16 + q * 4 + r) * NH + col] = f2bf(leaky_f(acc2[ct][r] + bv));
    }
}

// ============ RGCN layer, stage 1: xw[n, r, :] = x[n] @ W_r  (r=12 -> root) ============
__global__ __launch_bounds__(256) void xw_k(
    const unsigned short* __restrict__ xin,
    const unsigned short* __restrict__ Bxw,
    unsigned short* __restrict__ xw)
{
    const int wave = threadIdx.x >> 6, lane = threadIdx.x & 63;
    const int q = lane >> 4, cl = lane & 15;
    int wid = blockIdx.x * 4 + wave;
    if (wid >= MT2 * NRX) wid = MT2 * NRX - 1;   // clamp: duplicate identical stores
    __shared__ unsigned short tl[4][2][16][136];
    const int t2 = wid / NRX;
    const int r = wid - t2 * NRX;
    const int ta = t2 * 2;
    const int tb = (ta + 1 < MT) ? ta + 1 : MT - 1;   // clamp: duplicate identical stores

    floatx4 accA[8], accB[8];
#pragma unroll
    for (int ct = 0; ct < 8; ct++) {
        floatx4 z = {0.f,0.f,0.f,0.f}; accA[ct] = z; accB[ct] = z;
    }
#pragma unroll
    for (int ks = 0; ks < 4; ks++) {
        const short8 aA = *(const short8*)__builtin_assume_aligned(
            xin + (size_t)(ta * 16 + cl) * NH + ks * 32 + q * 8, 16);
        const short8 aB = *(const short8*)__builtin_assume_aligned(
            xin + (size_t)(tb * 16 + cl) * NH + ks * 32 + q * 8, 16);
#pragma unroll
        for (int ct = 0; ct < 8; ct++) {
            const short8 b = *(const short8*)(Bxw + ((size_t)((r * 8 + ct) * 4 + ks) * 64 + lane) * 8);
            accA[ct] = __builtin_amdgcn_mfma_f32_16x16x32_bf16(aA, b, accA[ct], 0, 0, 0);
            accB[ct] = __builtin_amdgcn_mfma_f32_16x16x32_bf16(aB, b, accB[ct], 0, 0, 0);
        }
    }
    // C-frag -> LDS (row-major bf16)
#pragma unroll
    for (int ct = 0; ct < 8; ct++) {
        const int col = ct * 16 + cl;
#pragma unroll
        for (int rr = 0; rr < 4; rr++) {
            tl[wave][0][q * 4 + rr][col] = f2bf(accA[ct][rr]);
            tl[wave][1][q * 4 + rr][col] = f2bf(accB[ct][rr]);
        }
    }
    __syncthreads();   // all 256 threads active (wid clamped)
    // read back row-major, 16B stores: per inst 16 lanes cover a full 256B row
#pragma unroll
    for (int i = 0; i < 4; i++) {
        const int row = i * 4 + q;
        const short8 vA = *(const short8*)&tl[wave][0][row][cl * 8];
        const short8 vB = *(const short8*)&tl[wave][1][row][cl * 8];
        *(short8*)(xw + ((size_t)(ta * 16 + row) * NRX + r) * NH + cl * 8) = vA;
        *(short8*)(xw + ((size_t)(tb * 16 + row) * NRX + r) * NH + cl * 8) = vB;
    }
}

// ============ RGCN layer, stage 2: uniform per-node gather-sum of transformed rows ======
// out[d] = sum_{e in edges(d)} (1/n_e) * xw[src_e, r_e]  +  xw[d, 12]  + bias
// 2 waves per 16-node tile; lane owns chunks cA=half*8+q, cB=cA+4 (all 16 chunks covered).
// Edge loop unrolled x4: 4 independent index loads + 8 independent row loads in flight.
// do_head: layer-2 variant stages rows in LDS and runs the Wo1/Wo2 head per tile
// (half-0 wave), eliminating the separate head kernel and the xa round-trip.
#define ACC8(fk, tv, wv) \
    fk[0] += (wv) * bf2f((tv).x & 0xFFFFu); fk[1] += (wv) * bf2f((tv).x >> 16); \
    fk[2] += (wv) * bf2f((tv).y & 0xFFFFu); fk[3] += (wv) * bf2f((tv).y >> 16); \
    fk[4] += (wv) * bf2f((tv).z & 0xFFFFu); fk[5] += (wv) * bf2f((tv).z >> 16); \
    fk[6] += (wv) * bf2f((tv).w & 0xFFFFu); fk[7] += (wv) * bf2f((tv).w >> 16);

#define INIT8(fk, tv) \
    fk[0] = bf2f((tv).x & 0xFFFFu); fk[1] = bf2f((tv).x >> 16); \
    fk[2] = bf2f((tv).y & 0xFFFFu); fk[3] = bf2f((tv).y >> 16); \
    fk[4] = bf2f((tv).z & 0xFFFFu); fk[5] = bf2f((tv).z >> 16); \
    fk[6] = bf2f((tv).w & 0xFFFFu); fk[7] = bf2f((tv).w >> 16);

__global__ __launch_bounds__(256) void gather_k(
    const unsigned short* __restrict__ xw,
    const unsigned int* __restrict__ eidx,
    const int* __restrict__ offs, const int* __restrict__ part,
    const float* __restrict__ rbias,
    unsigned short* __restrict__ xout,
    const int do_head,
    const unsigned short* __restrict__ Bo1, const float* __restrict__ bo1,
    const float* __restrict__ Wo2, const float* __restrict__ bo2,
    float* __restrict__ out)
{
    const int wave = threadIdx.x >> 6, lane = threadIdx.x & 63;
    const int q = lane >> 4, cl = lane & 15;
    int wid = blockIdx.x * 4 + wave;
    if (wid >= MT * 2) wid = MT * 2 - 1;     // clamp: duplicate identical work
    const int tile = wid >> 1;
    const int half = wid & 1;
    const int lt = wave >> 1;                // local tile slot (waves 0,1 / 2,3)
    __shared__ unsigned short lx[2][16][136];

    const int cA = half * 8 + q;             // 16B col chunk 0..15
    const int cB = cA + 4;
    const int d = tile * 16 + cl;
    const int s0 = d * NR;
    const int beg = offs[s0] + part[s0 >> 8];
    int end;
    if (d < NN - 1) { const int s1 = s0 + NR; end = offs[s1] + part[s1 >> 8]; }
    else end = NE;

    float fA[8], fB[8];
    {   // root contribution, weight 1
        const unsigned short* xr = xw + ((size_t)d * NRX + NR) * NH;
        const uint4 tA = *(const uint4*)(xr + cA * 8);
        const uint4 tB = *(const uint4*)(xr + cB * 8);
        INIT8(fA, tA); INIT8(fB, tB);
    }

    for (int e = beg; e < end; e += 4) {
        const int e1 = (e + 1 < end) ? e + 1 : e;
        const int e2 = (e + 2 < end) ? e + 2 : e;
        const int e3 = (e + 3 < end) ? e + 3 : e;
        const unsigned int v0 = eidx[e];
        const unsigned int v1 = eidx[e1];
        const unsigned int v2 = eidx[e2];
        const unsigned int v3 = eidx[e3];
        const float w0 = fast_rcp((float)(v0 >> 20));
        const float w1 = (e + 1 < end) ? fast_rcp((float)(v1 >> 20)) : 0.f;
        const float w2 = (e + 2 < end) ? fast_rcp((float)(v2 >> 20)) : 0.f;
        const float w3 = (e + 3 < end) ? fast_rcp((float)(v3 >> 20)) : 0.f;
        const unsigned short* x0 = xw + (size_t)(v0 & 0xFFFFFu) * NH;
        const unsigned short* x1 = xw + (size_t)(v1 & 0xFFFFFu) * NH;
        const unsigned short* x2 = xw + (size_t)(v2 & 0xFFFFFu) * NH;
        const unsigned short* x3 = xw + (size_t)(v3 & 0xFFFFFu) * NH;
        const uint4 a0 = *(const uint4*)(x0 + cA * 8);
        const uint4 b0 = *(const uint4*)(x0 + cB * 8);
        const uint4 a1 = *(const uint4*)(x1 + cA * 8);
        const uint4 b1 = *(const uint4*)(x1 + cB * 8);
        const uint4 a2 = *(const uint4*)(x2 + cA * 8);
        const uint4 b2 = *(const uint4*)(x2 + cB * 8);
        const uint4 a3 = *(const uint4*)(x3 + cA * 8);
        const uint4 b3 = *(const uint4*)(x3 + cB * 8);
        ACC8(fA, a0, w0); ACC8(fB, b0, w0);
        ACC8(fA, a1, w1); ACC8(fB, b1, w1);
        ACC8(fA, a2, w2); ACC8(fB, b2, w2);
        ACC8(fA, a3, w3); ACC8(fB, b3, w3);
    }

    union { short8 v; unsigned short u[8]; } oA, oB;
#pragma unroll
    for (int m = 0; m < 8; m++) {
        oA.u[m] = f2bf(fA[m] + rbias[cA * 8 + m]);
        oB.u[m] = f2bf(fB[m] + rbias[cB * 8 + m]);
    }

    if (!do_head) {
        *(short8*)(xout + (size_t)d * NH + cA * 8) = oA.v;
        *(short8*)(xout + (size_t)d * NH + cB * 8) = oB.v;
        return;
    }

    // -------- fused head: rows -> LDS, then leaky(x@Wo1+b) @ Wo2 + b2 --------
    *(short8*)&lx[lt][cl][cA * 8] = oA.v;
    *(short8*)&lx[lt][cl][cB * 8] = oB.v;
    __syncthreads();
    if (half == 0) {
        floatx4 acc[8];
#pragma unroll
        for (int ct = 0; ct < 8; ct++) { floatx4 z = {0.f,0.f,0.f,0.f}; acc[ct] = z; }
#pragma unroll
        for (int ks = 0; ks < 4; ks++) {
            const short8 a = *(const short8*)&lx[lt][cl][ks * 32 + q * 8];
#pragma unroll
            for (int ct = 0; ct < 8; ct++) {
                const short8 b = *(const short8*)(Bo1 + ((size_t)(ct * 4 + ks) * 64 + lane) * 8);
                acc[ct] = __builtin_amdgcn_mfma_f32_16x16x32_bf16(a, b, acc[ct], 0, 0, 0);
            }
        }
        // overwrite lx[lt] with leaky output (intra-wave DS ordering suffices)
#pragma unroll
        for (int ct = 0; ct < 8; ct++) {
            const int col = ct * 16 + cl;
            const float bv = bo1[col];
#pragma unroll
            for (int r2 = 0; r2 < 4; r2++)
                lx[lt][q * 4 + r2][col] = f2bf(leaky_f(acc[ct][r2] + bv));
        }
        if (lane < 32) {
            const int row = lane >> 1, o = lane & 1;
            float s = bo2[o];
            for (int k = 0; k < NH; k++)
                s += bf2f(lx[lt][row][k]) * Wo2[k * 2 + o];
            out[(size_t)(tile * 16 + row) * 2 + o] = s;
        }
    }
}

extern "C" void kernel_launch(void* const* d_in, const int* in_sizes, int n_in,
                              void* d_out, int out_size, void* d_ws, size_t ws_size,
                              hipStream_t stream)
{
    const float* feat = (const float*)d_in[0];
    const int* ei   = (const int*)d_in[1];
    const int* et   = (const int*)d_in[2];
    const float* Wdes = (const float*)d_in[3];
    const float* bdes = (const float*)d_in[4];
    const float* Wtw  = (const float*)d_in[5];
    const float* btw  = (const float*)d_in[6];
    const float* Wnum = (const float*)d_in[7];
    const float* bnum = (const float*)d_in[8];
    const float* Wcat = (const float*)d_in[9];
    const float* bcat = (const float*)d_in[10];
    const float* Win  = (const float*)d_in[11];
    const float* bin  = (const float*)d_in[12];
    const float* rgW  = (const float*)d_in[13];
    const float* root = (const float*)d_in[14];
    const float* rbias= (const float*)d_in[15];
    const float* Wo1  = (const float*)d_in[16];
    const float* bo1  = (const float*)d_in[17];
    const float* Wo2  = (const float*)d_in[18];
    const float* bo2  = (const float*)d_in[19];
    const int* srcp = ei;
    const int* dstp = ei + NE;

    // Workspace carve (~212 MiB)
    char* p = (char*)d_ws;
    auto alloc = [&](size_t bytes) { char* r = p; p += (bytes + 255) & ~(size_t)255; return r; };
    unsigned short* xa = (unsigned short*)alloc((size_t)NN * NH * 2);
    unsigned short* xb = (unsigned short*)alloc((size_t)NN * NH * 2);
    int* deg  = (int*)alloc((size_t)NSEG * 4);
    int* offs = (int*)alloc((size_t)NSEG * 4);
    int* cur  = (int*)alloc((size_t)NSEG * 4);
    int* part = (int*)alloc((size_t)(SCAN_NB + 8) * 4);
    unsigned int* eidx = (unsigned int*)alloc((size_t)NE * 4);
    unsigned short* Benc = (unsigned short*)alloc((size_t)TOTENC * 2);
    unsigned short* sWin = (unsigned short*)alloc((size_t)TOT128 * 2);
    unsigned short* Bxw  = (unsigned short*)alloc((size_t)TOTXW * 2);
    unsigned short* sWo1 = (unsigned short*)alloc((size_t)TOT128 * 2);
    float* be = (float*)alloc(128 * 4);
    unsigned short* xwbuf = (unsigned short*)alloc((size_t)NN * NRX * NH * 2);  // 166.4 MB

    const int GB = (MT + 3) / 4;            // 782 blocks of 4 waves
    const int GBXW = (MT2 * NRX + 3) / 4;   // 5080
    const int GB2 = (MT * 2 + 3) / 4;       // 1563 (gather: 2 waves/tile)

    // CSR build (scanC folded into fill/gather via part[])
    zero_k<<<SCAN_NB, 256, 0, stream>>>(deg, cur);
    hist_k<<<(NE + 255) / 256, 256, 0, stream>>>(dstp, et, deg);
    scanA_k<<<SCAN_NB, 256, 0, stream>>>(deg, offs, part);
    scanB_k<<<1, 256, 0, stream>>>(part, SCAN_NB);
    fill_k<<<(NE + 255) / 256, 256, 0, stream>>>(srcp, dstp, et, offs, part, deg, cur, eidx);

    // Weight prep (single dispatch)
    prep_k<<<(TOTPREP + 255) / 256, 256, 0, stream>>>(
        Wdes, Wtw, Wnum, Wcat, Win, rgW, root, Wo1,
        bdes, btw, bnum, bcat, Benc, sWin, Bxw, sWo1, be);

    // Fused pipeline
    enc_k<<<GB, 256, 0, stream>>>(feat, Benc, be, sWin, bin, xa);
    // layer 1
    xw_k<<<GBXW, 256, 0, stream>>>(xa, Bxw, xwbuf);
    gather_k<<<GB2, 256, 0, stream>>>(xwbuf, eidx, offs, part, rbias, xb, 0,
                                      sWo1, bo1, Wo2, bo2, (float*)d_out);
    // layer 2 + fused head
    xw_k<<<GBXW, 256, 0, stream>>>(xb, Bxw, xwbuf);
    gather_k<<<GB2, 256, 0, stream>>>(xwbuf, eidx, offs, part, rbias, xa, 1,
                                      sWo1, bo1, Wo2, bo2, (float*)d_out);
}